// Round 13
// baseline (2518.800 us; speedup 1.0000x reference)
//
#include <hip/hip_runtime.h>
#include <math.h>

#define N_NODES   32768
#define N_GRAPHS  64
#define NPG       512
#define N_EDGES   524288
#define D         128
#define N_ETYPES  4
#define N_STEPS   8

// ---------------------------------------------------------------------------
// Edge-type transform: tm[t][n][k] = sum_d h[n][d] * W[t][d][k]   (+bias)
// 256 threads, tile = 64 nodes x 128 cols for one etype.
// W_t staged through LDS in K-tiles of 8; 8 nodes x 4 cols per thread.
// LDS: hsT 34816 B + wl 4096 B = 38912 B -> 4 blocks/CU.
// ---------------------------------------------------------------------------
#define EKT 8
__global__ __launch_bounds__(256) void k_edge_transform(
    const float* __restrict__ h, const float* __restrict__ W,
    const float* __restrict__ b, float* __restrict__ tm)
{
    __shared__ float hsT[128 * 68];      // [d][n], pad 68
    __shared__ float wl[EKT * 128];      // W k-tile [dd][k]
    const int t   = blockIdx.y;
    const int n0  = blockIdx.x * 64;
    const int tid = threadIdx.x;

    #pragma unroll
    for (int it = 0; it < 32; ++it) {
        int idx = it * 256 + tid;
        int n = idx >> 7, d = idx & 127;
        hsT[d * 68 + n] = h[(size_t)(n0 + n) * D + d];
    }

    const int kq = tid & 31, k4 = kq * 4;
    const int ng = tid >> 5;
    const int nB = ng * 8;

    float acc[8][4];
    #pragma unroll
    for (int i = 0; i < 8; ++i)
        #pragma unroll
        for (int j = 0; j < 4; ++j) acc[i][j] = 0.f;

    const float* Wt = W + (size_t)t * D * D;
    for (int kt = 0; kt < D; kt += EKT) {
        __syncthreads();                 // covers hsT staging on first iter
        ((float4*)wl)[tid] = ((const float4*)(Wt + (size_t)kt * D))[tid];
        __syncthreads();
        #pragma unroll
        for (int dd = 0; dd < EKT; ++dd) {
            const int d = kt + dd;
            float4 w  = *(const float4*)(&wl[dd * 128 + k4]);
            float4 h0 = *(const float4*)(&hsT[d * 68 + nB]);
            float4 h1 = *(const float4*)(&hsT[d * 68 + nB + 4]);
            float hv[8] = {h0.x, h0.y, h0.z, h0.w, h1.x, h1.y, h1.z, h1.w};
            #pragma unroll
            for (int i = 0; i < 8; ++i) {
                acc[i][0] += hv[i] * w.x;
                acc[i][1] += hv[i] * w.y;
                acc[i][2] += hv[i] * w.z;
                acc[i][3] += hv[i] * w.w;
            }
        }
    }

    float4 bias = *(const float4*)(b + t * D + k4);
    float* outp = tm + (size_t)t * N_NODES * D + (size_t)n0 * D;
    #pragma unroll
    for (int i = 0; i < 8; ++i) {
        int n = nB + i;
        float4 v = make_float4(acc[i][0] + bias.x, acc[i][1] + bias.y,
                               acc[i][2] + bias.z, acc[i][3] + bias.w);
        *(float4*)(outp + (size_t)n * D + k4) = v;
    }
}

// ---------------------------------------------------------------------------
// CSR build (once per launch): histogram -> scan -> scatter of (src|etype)
// ---------------------------------------------------------------------------
__global__ void k_hist(const int* __restrict__ dst, int* __restrict__ cnt)
{
    int e = blockIdx.x * blockDim.x + threadIdx.x;
    if (e < N_EDGES) atomicAdd(&cnt[dst[e]], 1);
}

__global__ __launch_bounds__(1024) void k_scan(
    const int* __restrict__ cnt, int* __restrict__ row_start, int* __restrict__ cursor)
{
    __shared__ int part[1024];
    const int t = threadIdx.x;
    const int base = t * 32;

    int local[32];
    int s = 0;
    #pragma unroll
    for (int j = 0; j < 32; ++j) { local[j] = cnt[base + j]; s += local[j]; }
    part[t] = s;
    __syncthreads();

    for (int off = 1; off < 1024; off <<= 1) {
        int v   = part[t];
        int add = (t >= off) ? part[t - off] : 0;
        __syncthreads();
        part[t] = v + add;
        __syncthreads();
    }
    int ex = (t == 0) ? 0 : part[t - 1];

    if (t == 0) row_start[0] = 0;
    int run = ex;
    #pragma unroll
    for (int j = 0; j < 32; ++j) {
        cursor[base + j] = run;
        run += local[j];
        row_start[base + j + 1] = run;
    }
}

__global__ void k_scatter(const int* __restrict__ src, const int* __restrict__ dst,
                          const int* __restrict__ et, int* __restrict__ cursor,
                          int* __restrict__ sorted_se)
{
    int e = blockIdx.x * blockDim.x + threadIdx.x;
    if (e < N_EDGES) {
        int p = atomicAdd(&cursor[dst[e]], 1);
        sorted_se[p] = src[e] | (et[e] << 15);
    }
}

// ---------------------------------------------------------------------------
// Weight transpose (once per launch): w[384][128] -> wT[128][384]
// ---------------------------------------------------------------------------
__global__ void k_transpose(const float* __restrict__ w, float* __restrict__ wT)
{
    int id = blockIdx.x * blockDim.x + threadIdx.x;
    int j = id >> 7, d = id & 127;
    wT[d * 384 + j] = w[id];
}

// ---------------------------------------------------------------------------
// FUSED gather + GRU: per block of 32 nodes,
//   phase 1: gather a[n] = sum_{edges into n} tm[etype][src] directly into
//            aT LDS (wave w handles nodes w*8..w*8+7; float2 per lane) —
//            eliminates the global `a` buffer and lets gather's L3 latency
//            hide under other blocks' GRU FMAs on the same CU.
//   phase 2: GRU with r/z-fused accumulators, weights LDS-staged (GKT=4).
// LDS: aT+hT 36864 B + wl 12288 B = 49152 B -> 3 blocks/CU.
// ---------------------------------------------------------------------------
#define GKT 4
__global__ __launch_bounds__(256, 3) void k_gather_gru(
    const float* __restrict__ tm, const int* __restrict__ row_start,
    const int* __restrict__ sorted_se,
    float* __restrict__ h,
    const float* __restrict__ wihT, const float* __restrict__ whhT,
    const float* __restrict__ bih, const float* __restrict__ bhh)
{
    __shared__ float aT[128 * 36];           // [d][n], 144B rows
    __shared__ float hT[128 * 36];
    __shared__ float wl[2][GKT * 384];       // k-tile: [ih/hh][dd][j]
    const int n0  = blockIdx.x * 32;
    const int tid = threadIdx.x;

    // stage hT (coalesced)
    #pragma unroll
    for (int it = 0; it < 16; ++it) {
        int idx = it * 256 + tid;
        int n = idx >> 7, d = idx & 127;
        hT[d * 36 + n] = h[(size_t)(n0 + n) * D + d];
    }

    // phase 1: gather into aT. wave w -> nodes w*8 .. w*8+7
    {
        const int wave = tid >> 6, lane = tid & 63;
        for (int i = 0; i < 8; ++i) {
            const int nl   = wave * 8 + i;        // node local index
            const int node = n0 + nl;
            const int s0 = row_start[node], s1 = row_start[node + 1];
            float ax = 0.f, ay = 0.f;
            for (int j = s0; j < s1; ++j) {
                int se = sorted_se[j];
                int s = se & 32767, t = se >> 15;
                float2 v = ((const float2*)(tm + ((size_t)t * N_NODES + s) * D))[lane];
                ax += v.x; ay += v.y;
            }
            aT[(2 * lane)     * 36 + nl] = ax;
            aT[(2 * lane + 1) * 36 + nl] = ay;
        }
    }

    const int kq = tid & 31, k4 = kq * 4;
    const int ng = tid >> 5;          // 4 nodes: ng*4 .. +3
    const int nA = ng * 4;

    float grz[4][2][4];               // fused (i_r+h_r), (i_z+h_z)
    float gin[4][4], ghn[4][4];       // i_n, h_n kept separate
    {
        float4 br = *(const float4*)(bih + k4);
        float4 bz = *(const float4*)(bih + 128 + k4);
        float4 bn = *(const float4*)(bih + 256 + k4);
        float4 cr = *(const float4*)(bhh + k4);
        float4 cz = *(const float4*)(bhh + 128 + k4);
        float4 cn = *(const float4*)(bhh + 256 + k4);
        float rz0[4] = {br.x + cr.x, br.y + cr.y, br.z + cr.z, br.w + cr.w};
        float rz1[4] = {bz.x + cz.x, bz.y + cz.y, bz.z + cz.z, bz.w + cz.w};
        float inb[4] = {bn.x, bn.y, bn.z, bn.w};
        float hnb[4] = {cn.x, cn.y, cn.z, cn.w};
        #pragma unroll
        for (int i = 0; i < 4; ++i)
            #pragma unroll
            for (int j = 0; j < 4; ++j) {
                grz[i][0][j] = rz0[j];
                grz[i][1][j] = rz1[j];
                gin[i][j]    = inb[j];
                ghn[i][j]    = hnb[j];
            }
    }

    // phase 2: GRU matmuls with LDS-staged weights
    for (int kt = 0; kt < D; kt += GKT) {
        __syncthreads();                 // covers hT/aT staging on first iter
        {
            const float4* s0 = (const float4*)(wihT + (size_t)kt * 384);
            const float4* s1 = (const float4*)(whhT + (size_t)kt * 384);
            float4* d0 = (float4*)wl[0];
            float4* d1 = (float4*)wl[1];
            d0[tid] = s0[tid];
            d1[tid] = s1[tid];
            if (tid < 128) {             // wave-uniform branch (waves 0,1)
                d0[256 + tid] = s0[256 + tid];
                d1[256 + tid] = s1[256 + tid];
            }
        }
        __syncthreads();
        #pragma unroll
        for (int dd = 0; dd < GKT; ++dd) {
            const int d = kt + dd;
            float4 av = *(const float4*)(&aT[d * 36 + nA]);
            float4 hv = *(const float4*)(&hT[d * 36 + nA]);
            float avv[4] = {av.x, av.y, av.z, av.w};
            float hvv[4] = {hv.x, hv.y, hv.z, hv.w};
            float4 wir = *(const float4*)(&wl[0][dd * 384 + k4]);
            float4 wiz = *(const float4*)(&wl[0][dd * 384 + 128 + k4]);
            float4 win = *(const float4*)(&wl[0][dd * 384 + 256 + k4]);
            float4 whr = *(const float4*)(&wl[1][dd * 384 + k4]);
            float4 whz = *(const float4*)(&wl[1][dd * 384 + 128 + k4]);
            float4 whn = *(const float4*)(&wl[1][dd * 384 + 256 + k4]);
            float wirv[4] = {wir.x, wir.y, wir.z, wir.w};
            float wizv[4] = {wiz.x, wiz.y, wiz.z, wiz.w};
            float winv[4] = {win.x, win.y, win.z, win.w};
            float whrv[4] = {whr.x, whr.y, whr.z, whr.w};
            float whzv[4] = {whz.x, whz.y, whz.z, whz.w};
            float whnv[4] = {whn.x, whn.y, whn.z, whn.w};
            #pragma unroll
            for (int i = 0; i < 4; ++i)
                #pragma unroll
                for (int j = 0; j < 4; ++j) {
                    grz[i][0][j] += avv[i] * wirv[j];
                    grz[i][0][j] += hvv[i] * whrv[j];
                    grz[i][1][j] += avv[i] * wizv[j];
                    grz[i][1][j] += hvv[i] * whzv[j];
                    gin[i][j]    += avv[i] * winv[j];
                    ghn[i][j]    += hvv[i] * whnv[j];
                }
        }
    }

    #pragma unroll
    for (int i = 0; i < 4; ++i) {
        int n = n0 + nA + i;
        float hnew[4];
        #pragma unroll
        for (int j = 0; j < 4; ++j) {
            float r  = 1.f / (1.f + __expf(-grz[i][0][j]));
            float z  = 1.f / (1.f + __expf(-grz[i][1][j]));
            float nx = gin[i][j] + r * ghn[i][j];
            float nn = 2.f / (1.f + __expf(-2.f * nx)) - 1.f;   // tanh
            float ho = hT[(k4 + j) * 36 + nA + i];
            hnew[j] = (1.f - z) * nn + z * ho;
        }
        *(float4*)(h + (size_t)n * D + k4) = make_float4(hnew[0], hnew[1], hnew[2], hnew[3]);
    }
}

// ---------------------------------------------------------------------------
// Readout: out[g] = sigmoid( sum_nodes(h) . w_cls + b_cls )
// ---------------------------------------------------------------------------
__global__ __launch_bounds__(256) void k_readout(
    const float* __restrict__ h, const float* __restrict__ w_cls,
    const float* __restrict__ b_cls, float* __restrict__ out)
{
    __shared__ float sbuf[256];
    const int g = blockIdx.x;
    const int tid = threadIdx.x;
    const int k = tid & 127, half = tid >> 7;

    float s = 0.f;
    for (int r = half; r < NPG; r += 2)
        s += h[((size_t)g * NPG + r) * D + k];
    sbuf[tid] = s;
    __syncthreads();

    if (tid < 64) {
        int l = tid;
        float v = (sbuf[l]      + sbuf[l + 128]) * w_cls[l]
                + (sbuf[l + 64] + sbuf[l + 192]) * w_cls[l + 64];
        #pragma unroll
        for (int off = 32; off > 0; off >>= 1) v += __shfl_down(v, off);
        if (l == 0) out[g] = 1.f / (1.f + __expf(-(v + b_cls[0])));
    }
}

// ---------------------------------------------------------------------------
extern "C" void kernel_launch(void* const* d_in, const int* in_sizes, int n_in,
                              void* d_out, int out_size, void* d_ws, size_t ws_size,
                              hipStream_t stream)
{
    const float* feat   = (const float*)d_in[0];
    const float* W_edge = (const float*)d_in[1];
    const float* b_edge = (const float*)d_in[2];
    const float* w_ih   = (const float*)d_in[3];
    const float* w_hh   = (const float*)d_in[4];
    const float* b_ih   = (const float*)d_in[5];
    const float* b_hh   = (const float*)d_in[6];
    const float* w_cls  = (const float*)d_in[7];
    const float* b_cls  = (const float*)d_in[8];
    const int*   src    = (const int*)d_in[9];
    const int*   dst    = (const int*)d_in[10];
    const int*   et     = (const int*)d_in[11];
    float* out = (float*)d_out;

    char* ws = (char*)d_ws;
    size_t off = 0;
    auto alloc = [&](size_t bytes) -> void* {
        void* p = ws + off;
        off += (bytes + 255) & ~(size_t)255;
        return p;
    };

    float* h         = (float*)alloc((size_t)N_NODES * D * 4);
    float* tm        = (float*)alloc((size_t)N_ETYPES * N_NODES * D * 4);
    int*   cnt       = (int*)alloc((size_t)N_NODES * 4);
    int*   cursor    = (int*)alloc((size_t)N_NODES * 4);
    int*   row_start = (int*)alloc((size_t)(N_NODES + 1) * 4);
    int*   sorted_se = (int*)alloc((size_t)N_EDGES * 4);
    float* wihT      = (float*)alloc((size_t)384 * D * 4);
    float* whhT      = (float*)alloc((size_t)384 * D * 4);

    hipMemcpyAsync(h, feat, (size_t)N_NODES * D * 4, hipMemcpyDeviceToDevice, stream);

    hipMemsetAsync(cnt, 0, (size_t)N_NODES * 4, stream);
    k_hist<<<N_EDGES / 256, 256, 0, stream>>>(dst, cnt);
    k_scan<<<1, 1024, 0, stream>>>(cnt, row_start, cursor);
    k_scatter<<<N_EDGES / 256, 256, 0, stream>>>(src, dst, et, cursor, sorted_se);
    k_transpose<<<(384 * D) / 256, 256, 0, stream>>>(w_ih, wihT);
    k_transpose<<<(384 * D) / 256, 256, 0, stream>>>(w_hh, whhT);

    for (int step = 0; step < N_STEPS; ++step) {
        k_edge_transform<<<dim3(N_NODES / 64, N_ETYPES), 256, 0, stream>>>(h, W_edge, b_edge, tm);
        k_gather_gru<<<N_NODES / 32, 256, 0, stream>>>(tm, row_start, sorted_se,
                                                       h, wihT, whhT, b_ih, b_hh);
    }

    k_readout<<<N_GRAPHS, 256, 0, stream>>>(h, w_cls, b_cls, out);
}

// Round 14
// 1724.432 us; speedup vs baseline: 1.4607x; 1.4607x over previous
//
#include <hip/hip_runtime.h>
#include <math.h>

#define N_NODES   32768
#define N_GRAPHS  64
#define NPG       512
#define N_EDGES   524288
#define D         128
#define N_ETYPES  4
#define N_STEPS   8

typedef unsigned int  uint32;
typedef unsigned short ushort16;

// f32 -> bf16 (round-to-nearest-even) and back
__device__ __forceinline__ ushort16 f2bf(float f) {
    uint32 u = __float_as_uint(f);
    u = u + 0x7FFFu + ((u >> 16) & 1u);
    return (ushort16)(u >> 16);
}
__device__ __forceinline__ float bf2f(ushort16 s) {
    return __uint_as_float(((uint32)s) << 16);
}

// ---------------------------------------------------------------------------
// Edge-type transform: tm[t][n][k] = bf16( sum_d h[n][d]*W[t][d][k] + b )
// 256 threads, tile = 64 nodes x 128 cols for one etype.
// W_t staged through LDS in K-tiles of 8; 8 nodes x 4 cols per thread.
// tm stored bf16: halves write traffic and gather's random-read volume.
// LDS: hsT 34816 B + wl 4096 B = 38912 B -> 4 blocks/CU.
// ---------------------------------------------------------------------------
#define EKT 8
__global__ __launch_bounds__(256) void k_edge_transform(
    const float* __restrict__ h, const float* __restrict__ W,
    const float* __restrict__ b, ushort16* __restrict__ tm)
{
    __shared__ float hsT[128 * 68];      // [d][n], pad 68
    __shared__ float wl[EKT * 128];      // W k-tile [dd][k]
    const int t   = blockIdx.y;
    const int n0  = blockIdx.x * 64;
    const int tid = threadIdx.x;

    #pragma unroll
    for (int it = 0; it < 32; ++it) {
        int idx = it * 256 + tid;
        int n = idx >> 7, d = idx & 127;
        hsT[d * 68 + n] = h[(size_t)(n0 + n) * D + d];
    }

    const int kq = tid & 31, k4 = kq * 4;
    const int ng = tid >> 5;
    const int nB = ng * 8;

    float acc[8][4];
    #pragma unroll
    for (int i = 0; i < 8; ++i)
        #pragma unroll
        for (int j = 0; j < 4; ++j) acc[i][j] = 0.f;

    const float* Wt = W + (size_t)t * D * D;
    for (int kt = 0; kt < D; kt += EKT) {
        __syncthreads();                 // covers hsT staging on first iter
        ((float4*)wl)[tid] = ((const float4*)(Wt + (size_t)kt * D))[tid];
        __syncthreads();
        #pragma unroll
        for (int dd = 0; dd < EKT; ++dd) {
            const int d = kt + dd;
            float4 w  = *(const float4*)(&wl[dd * 128 + k4]);
            float4 h0 = *(const float4*)(&hsT[d * 68 + nB]);
            float4 h1 = *(const float4*)(&hsT[d * 68 + nB + 4]);
            float hv[8] = {h0.x, h0.y, h0.z, h0.w, h1.x, h1.y, h1.z, h1.w};
            #pragma unroll
            for (int i = 0; i < 8; ++i) {
                acc[i][0] += hv[i] * w.x;
                acc[i][1] += hv[i] * w.y;
                acc[i][2] += hv[i] * w.z;
                acc[i][3] += hv[i] * w.w;
            }
        }
    }

    float4 bias = *(const float4*)(b + t * D + k4);
    ushort16* outp = tm + (size_t)t * N_NODES * D + (size_t)n0 * D;
    #pragma unroll
    for (int i = 0; i < 8; ++i) {
        int n = nB + i;
        ushort4 v;
        v.x = f2bf(acc[i][0] + bias.x);
        v.y = f2bf(acc[i][1] + bias.y);
        v.z = f2bf(acc[i][2] + bias.z);
        v.w = f2bf(acc[i][3] + bias.w);
        *(ushort4*)(outp + (size_t)n * D + k4) = v;
    }
}

// ---------------------------------------------------------------------------
// CSR build (once per launch): histogram -> scan -> scatter of (src|etype)
// ---------------------------------------------------------------------------
__global__ void k_hist(const int* __restrict__ dst, int* __restrict__ cnt)
{
    int e = blockIdx.x * blockDim.x + threadIdx.x;
    if (e < N_EDGES) atomicAdd(&cnt[dst[e]], 1);
}

__global__ __launch_bounds__(1024) void k_scan(
    const int* __restrict__ cnt, int* __restrict__ row_start, int* __restrict__ cursor)
{
    __shared__ int part[1024];
    const int t = threadIdx.x;
    const int base = t * 32;

    int local[32];
    int s = 0;
    #pragma unroll
    for (int j = 0; j < 32; ++j) { local[j] = cnt[base + j]; s += local[j]; }
    part[t] = s;
    __syncthreads();

    for (int off = 1; off < 1024; off <<= 1) {
        int v   = part[t];
        int add = (t >= off) ? part[t - off] : 0;
        __syncthreads();
        part[t] = v + add;
        __syncthreads();
    }
    int ex = (t == 0) ? 0 : part[t - 1];

    if (t == 0) row_start[0] = 0;
    int run = ex;
    #pragma unroll
    for (int j = 0; j < 32; ++j) {
        cursor[base + j] = run;
        run += local[j];
        row_start[base + j + 1] = run;
    }
}

__global__ void k_scatter(const int* __restrict__ src, const int* __restrict__ dst,
                          const int* __restrict__ et, int* __restrict__ cursor,
                          int* __restrict__ sorted_se)
{
    int e = blockIdx.x * blockDim.x + threadIdx.x;
    if (e < N_EDGES) {
        int p = atomicAdd(&cursor[dst[e]], 1);
        sorted_se[p] = src[e] | (et[e] << 15);
    }
}

// ---------------------------------------------------------------------------
// Gather: a[n][:] = sum over incoming edges of bf16 tm[etype][src][:]
// one 64-lane wave per node; each lane owns 2 consecutive d (uint = 2x bf16).
// 2-way edge unroll keeps 2 rows in flight per wave.
// ---------------------------------------------------------------------------
__global__ __launch_bounds__(256) void k_gather(
    const ushort16* __restrict__ tm, const int* __restrict__ row_start,
    const int* __restrict__ sorted_se, float* __restrict__ a)
{
    const int node = blockIdx.x * 4 + (threadIdx.x >> 6);
    const int lane = threadIdx.x & 63;
    const int s0 = row_start[node], s1 = row_start[node + 1];

    float ax = 0.f, ay = 0.f;
    int j = s0;
    for (; j + 1 < s1; j += 2) {
        int se0 = sorted_se[j],     se1 = sorted_se[j + 1];
        int sA = se0 & 32767, tA = se0 >> 15;
        int sB = se1 & 32767, tB = se1 >> 15;
        uint32 vA = ((const uint32*)(tm + ((size_t)tA * N_NODES + sA) * D))[lane];
        uint32 vB = ((const uint32*)(tm + ((size_t)tB * N_NODES + sB) * D))[lane];
        ax += bf2f((ushort16)(vA & 0xFFFF)) + bf2f((ushort16)(vB & 0xFFFF));
        ay += bf2f((ushort16)(vA >> 16))    + bf2f((ushort16)(vB >> 16));
    }
    if (j < s1) {
        int se = sorted_se[j];
        int s = se & 32767, t = se >> 15;
        uint32 v = ((const uint32*)(tm + ((size_t)t * N_NODES + s) * D))[lane];
        ax += bf2f((ushort16)(v & 0xFFFF));
        ay += bf2f((ushort16)(v >> 16));
    }
    float* ap = a + (size_t)node * D + 2 * lane;
    ap[0] = ax;
    ap[1] = ay;
}

// ---------------------------------------------------------------------------
// Weight transpose (once per launch): w[384][128] -> wT[128][384]
// ---------------------------------------------------------------------------
__global__ void k_transpose(const float* __restrict__ w, float* __restrict__ wT)
{
    int id = blockIdx.x * blockDim.x + threadIdx.x;
    int j = id >> 7, d = id & 127;
    wT[d * 384 + j] = w[id];
}

// ---------------------------------------------------------------------------
// Fused GRU cell: h = GRU(a, h)  (in-place, 32 nodes per block)
// r/z-fused accumulation -> 64 accs/thread; weights LDS-staged in K-tiles of 4.
// LDS: aT+hT 36864 B + wl 12288 B = 49152 B -> 3 blocks/CU.
// GRID: N_NODES/32 = 1024 blocks.
// ---------------------------------------------------------------------------
#define GKT 4
__global__ __launch_bounds__(256, 3) void k_gru(
    const float* __restrict__ a, float* __restrict__ h,
    const float* __restrict__ wihT, const float* __restrict__ whhT,
    const float* __restrict__ bih, const float* __restrict__ bhh)
{
    __shared__ float aT[128 * 36];           // [d][n], 144B rows
    __shared__ float hT[128 * 36];
    __shared__ float wl[2][GKT * 384];       // k-tile: [ih/hh][dd][j]
    const int n0  = blockIdx.x * 32;
    const int tid = threadIdx.x;

    #pragma unroll
    for (int it = 0; it < 16; ++it) {
        int idx = it * 256 + tid;
        int n = idx >> 7, d = idx & 127;
        aT[d * 36 + n] = a[(size_t)(n0 + n) * D + d];
        hT[d * 36 + n] = h[(size_t)(n0 + n) * D + d];
    }

    const int kq = tid & 31, k4 = kq * 4;
    const int ng = tid >> 5;          // 4 nodes: ng*4 .. +3
    const int nA = ng * 4;

    float grz[4][2][4];               // fused (i_r+h_r), (i_z+h_z)
    float gin[4][4], ghn[4][4];       // i_n, h_n kept separate
    {
        float4 br = *(const float4*)(bih + k4);
        float4 bz = *(const float4*)(bih + 128 + k4);
        float4 bn = *(const float4*)(bih + 256 + k4);
        float4 cr = *(const float4*)(bhh + k4);
        float4 cz = *(const float4*)(bhh + 128 + k4);
        float4 cn = *(const float4*)(bhh + 256 + k4);
        float rz0[4] = {br.x + cr.x, br.y + cr.y, br.z + cr.z, br.w + cr.w};
        float rz1[4] = {bz.x + cz.x, bz.y + cz.y, bz.z + cz.z, bz.w + cz.w};
        float inb[4] = {bn.x, bn.y, bn.z, bn.w};
        float hnb[4] = {cn.x, cn.y, cn.z, cn.w};
        #pragma unroll
        for (int i = 0; i < 4; ++i)
            #pragma unroll
            for (int j = 0; j < 4; ++j) {
                grz[i][0][j] = rz0[j];
                grz[i][1][j] = rz1[j];
                gin[i][j]    = inb[j];
                ghn[i][j]    = hnb[j];
            }
    }

    for (int kt = 0; kt < D; kt += GKT) {
        __syncthreads();                 // covers aT/hT staging on first iter
        {
            const float4* s0 = (const float4*)(wihT + (size_t)kt * 384);
            const float4* s1 = (const float4*)(whhT + (size_t)kt * 384);
            float4* d0 = (float4*)wl[0];
            float4* d1 = (float4*)wl[1];
            d0[tid] = s0[tid];
            d1[tid] = s1[tid];
            if (tid < 128) {             // wave-uniform branch (waves 0,1)
                d0[256 + tid] = s0[256 + tid];
                d1[256 + tid] = s1[256 + tid];
            }
        }
        __syncthreads();
        #pragma unroll
        for (int dd = 0; dd < GKT; ++dd) {
            const int d = kt + dd;
            float4 av = *(const float4*)(&aT[d * 36 + nA]);
            float4 hv = *(const float4*)(&hT[d * 36 + nA]);
            float avv[4] = {av.x, av.y, av.z, av.w};
            float hvv[4] = {hv.x, hv.y, hv.z, hv.w};
            float4 wir = *(const float4*)(&wl[0][dd * 384 + k4]);
            float4 wiz = *(const float4*)(&wl[0][dd * 384 + 128 + k4]);
            float4 win = *(const float4*)(&wl[0][dd * 384 + 256 + k4]);
            float4 whr = *(const float4*)(&wl[1][dd * 384 + k4]);
            float4 whz = *(const float4*)(&wl[1][dd * 384 + 128 + k4]);
            float4 whn = *(const float4*)(&wl[1][dd * 384 + 256 + k4]);
            float wirv[4] = {wir.x, wir.y, wir.z, wir.w};
            float wizv[4] = {wiz.x, wiz.y, wiz.z, wiz.w};
            float winv[4] = {win.x, win.y, win.z, win.w};
            float whrv[4] = {whr.x, whr.y, whr.z, whr.w};
            float whzv[4] = {whz.x, whz.y, whz.z, whz.w};
            float whnv[4] = {whn.x, whn.y, whn.z, whn.w};
            #pragma unroll
            for (int i = 0; i < 4; ++i)
                #pragma unroll
                for (int j = 0; j < 4; ++j) {
                    grz[i][0][j] += avv[i] * wirv[j];
                    grz[i][0][j] += hvv[i] * whrv[j];
                    grz[i][1][j] += avv[i] * wizv[j];
                    grz[i][1][j] += hvv[i] * whzv[j];
                    gin[i][j]    += avv[i] * winv[j];
                    ghn[i][j]    += hvv[i] * whnv[j];
                }
        }
    }

    #pragma unroll
    for (int i = 0; i < 4; ++i) {
        int n = n0 + nA + i;
        float hnew[4];
        #pragma unroll
        for (int j = 0; j < 4; ++j) {
            float r  = 1.f / (1.f + __expf(-grz[i][0][j]));
            float z  = 1.f / (1.f + __expf(-grz[i][1][j]));
            float nx = gin[i][j] + r * ghn[i][j];
            float nn = 2.f / (1.f + __expf(-2.f * nx)) - 1.f;   // tanh
            float ho = hT[(k4 + j) * 36 + nA + i];
            hnew[j] = (1.f - z) * nn + z * ho;
        }
        *(float4*)(h + (size_t)n * D + k4) = make_float4(hnew[0], hnew[1], hnew[2], hnew[3]);
    }
}

// ---------------------------------------------------------------------------
// Readout: out[g] = sigmoid( sum_nodes(h) . w_cls + b_cls )
// ---------------------------------------------------------------------------
__global__ __launch_bounds__(256) void k_readout(
    const float* __restrict__ h, const float* __restrict__ w_cls,
    const float* __restrict__ b_cls, float* __restrict__ out)
{
    __shared__ float sbuf[256];
    const int g = blockIdx.x;
    const int tid = threadIdx.x;
    const int k = tid & 127, half = tid >> 7;

    float s = 0.f;
    for (int r = half; r < NPG; r += 2)
        s += h[((size_t)g * NPG + r) * D + k];
    sbuf[tid] = s;
    __syncthreads();

    if (tid < 64) {
        int l = tid;
        float v = (sbuf[l]      + sbuf[l + 128]) * w_cls[l]
                + (sbuf[l + 64] + sbuf[l + 192]) * w_cls[l + 64];
        #pragma unroll
        for (int off = 32; off > 0; off >>= 1) v += __shfl_down(v, off);
        if (l == 0) out[g] = 1.f / (1.f + __expf(-(v + b_cls[0])));
    }
}

// ---------------------------------------------------------------------------
extern "C" void kernel_launch(void* const* d_in, const int* in_sizes, int n_in,
                              void* d_out, int out_size, void* d_ws, size_t ws_size,
                              hipStream_t stream)
{
    const float* feat   = (const float*)d_in[0];
    const float* W_edge = (const float*)d_in[1];
    const float* b_edge = (const float*)d_in[2];
    const float* w_ih   = (const float*)d_in[3];
    const float* w_hh   = (const float*)d_in[4];
    const float* b_ih   = (const float*)d_in[5];
    const float* b_hh   = (const float*)d_in[6];
    const float* w_cls  = (const float*)d_in[7];
    const float* b_cls  = (const float*)d_in[8];
    const int*   src    = (const int*)d_in[9];
    const int*   dst    = (const int*)d_in[10];
    const int*   et     = (const int*)d_in[11];
    float* out = (float*)d_out;

    char* ws = (char*)d_ws;
    size_t off = 0;
    auto alloc = [&](size_t bytes) -> void* {
        void* p = ws + off;
        off += (bytes + 255) & ~(size_t)255;
        return p;
    };

    float*    h         = (float*)alloc((size_t)N_NODES * D * 4);
    float*    a         = (float*)alloc((size_t)N_NODES * D * 4);
    ushort16* tm        = (ushort16*)alloc((size_t)N_ETYPES * N_NODES * D * 2);
    int*      cnt       = (int*)alloc((size_t)N_NODES * 4);
    int*      cursor    = (int*)alloc((size_t)N_NODES * 4);
    int*      row_start = (int*)alloc((size_t)(N_NODES + 1) * 4);
    int*      sorted_se = (int*)alloc((size_t)N_EDGES * 4);
    float*    wihT      = (float*)alloc((size_t)384 * D * 4);
    float*    whhT      = (float*)alloc((size_t)384 * D * 4);

    hipMemcpyAsync(h, feat, (size_t)N_NODES * D * 4, hipMemcpyDeviceToDevice, stream);

    hipMemsetAsync(cnt, 0, (size_t)N_NODES * 4, stream);
    k_hist<<<N_EDGES / 256, 256, 0, stream>>>(dst, cnt);
    k_scan<<<1, 1024, 0, stream>>>(cnt, row_start, cursor);
    k_scatter<<<N_EDGES / 256, 256, 0, stream>>>(src, dst, et, cursor, sorted_se);
    k_transpose<<<(384 * D) / 256, 256, 0, stream>>>(w_ih, wihT);
    k_transpose<<<(384 * D) / 256, 256, 0, stream>>>(w_hh, whhT);

    for (int step = 0; step < N_STEPS; ++step) {
        k_edge_transform<<<dim3(N_NODES / 64, N_ETYPES), 256, 0, stream>>>(h, W_edge, b_edge, tm);
        k_gather<<<N_NODES / 4, 256, 0, stream>>>(tm, row_start, sorted_se, a);
        k_gru<<<N_NODES / 32, 256, 0, stream>>>(a, h, wihT, whhT, b_ih, b_hh);
    }

    k_readout<<<N_GRAPHS, 256, 0, stream>>>(h, w_cls, b_cls, out);
}

// Round 16
// 1236.455 us; speedup vs baseline: 2.0371x; 1.3947x over previous
//
#include <hip/hip_runtime.h>
#include <math.h>

#define N_NODES   32768
#define N_GRAPHS  64
#define NPG       512
#define N_EDGES   524288
#define D         128
#define N_ETYPES  4
#define N_STEPS   8

typedef unsigned int   uint32;
typedef unsigned short ushort16;
typedef __attribute__((ext_vector_type(8))) short bf16x8;   // 8 bf16 (4 VGPRs)
typedef __attribute__((ext_vector_type(4))) float f32x4;    // MFMA accumulator

// f32 -> bf16 (round-to-nearest-even) and back
__device__ __forceinline__ ushort16 f2bf(float f) {
    uint32 u = __float_as_uint(f);
    u = u + 0x7FFFu + ((u >> 16) & 1u);
    return (ushort16)(u >> 16);
}
__device__ __forceinline__ float bf2f(ushort16 s) {
    return __uint_as_float(((uint32)s) << 16);
}

// ---------------------------------------------------------------------------
// Edge-type transform: tm[t][n][k] = bf16( sum_d h[n][d]*W[t][d][k] + b )
// (unchanged from R14: LDS-staged W, 64-node tile, bf16 output)
// ---------------------------------------------------------------------------
#define EKT 8
__global__ __launch_bounds__(256) void k_edge_transform(
    const float* __restrict__ h, const float* __restrict__ W,
    const float* __restrict__ b, ushort16* __restrict__ tm)
{
    __shared__ float hsT[128 * 68];
    __shared__ float wl[EKT * 128];
    const int t   = blockIdx.y;
    const int n0  = blockIdx.x * 64;
    const int tid = threadIdx.x;

    #pragma unroll
    for (int it = 0; it < 32; ++it) {
        int idx = it * 256 + tid;
        int n = idx >> 7, d = idx & 127;
        hsT[d * 68 + n] = h[(size_t)(n0 + n) * D + d];
    }

    const int kq = tid & 31, k4 = kq * 4;
    const int ng = tid >> 5;
    const int nB = ng * 8;

    float acc[8][4];
    #pragma unroll
    for (int i = 0; i < 8; ++i)
        #pragma unroll
        for (int j = 0; j < 4; ++j) acc[i][j] = 0.f;

    const float* Wt = W + (size_t)t * D * D;
    for (int kt = 0; kt < D; kt += EKT) {
        __syncthreads();
        ((float4*)wl)[tid] = ((const float4*)(Wt + (size_t)kt * D))[tid];
        __syncthreads();
        #pragma unroll
        for (int dd = 0; dd < EKT; ++dd) {
            const int d = kt + dd;
            float4 w  = *(const float4*)(&wl[dd * 128 + k4]);
            float4 h0 = *(const float4*)(&hsT[d * 68 + nB]);
            float4 h1 = *(const float4*)(&hsT[d * 68 + nB + 4]);
            float hv[8] = {h0.x, h0.y, h0.z, h0.w, h1.x, h1.y, h1.z, h1.w};
            #pragma unroll
            for (int i = 0; i < 8; ++i) {
                acc[i][0] += hv[i] * w.x;
                acc[i][1] += hv[i] * w.y;
                acc[i][2] += hv[i] * w.z;
                acc[i][3] += hv[i] * w.w;
            }
        }
    }

    float4 bias = *(const float4*)(b + t * D + k4);
    ushort16* outp = tm + (size_t)t * N_NODES * D + (size_t)n0 * D;
    #pragma unroll
    for (int i = 0; i < 8; ++i) {
        int n = nB + i;
        ushort4 v;
        v.x = f2bf(acc[i][0] + bias.x);
        v.y = f2bf(acc[i][1] + bias.y);
        v.z = f2bf(acc[i][2] + bias.z);
        v.w = f2bf(acc[i][3] + bias.w);
        *(ushort4*)(outp + (size_t)n * D + k4) = v;
    }
}

// ---------------------------------------------------------------------------
// CSR build (once per launch)
// ---------------------------------------------------------------------------
__global__ void k_hist(const int* __restrict__ dst, int* __restrict__ cnt)
{
    int e = blockIdx.x * blockDim.x + threadIdx.x;
    if (e < N_EDGES) atomicAdd(&cnt[dst[e]], 1);
}

__global__ __launch_bounds__(1024) void k_scan(
    const int* __restrict__ cnt, int* __restrict__ row_start, int* __restrict__ cursor)
{
    __shared__ int part[1024];
    const int t = threadIdx.x;
    const int base = t * 32;

    int local[32];
    int s = 0;
    #pragma unroll
    for (int j = 0; j < 32; ++j) { local[j] = cnt[base + j]; s += local[j]; }
    part[t] = s;
    __syncthreads();

    for (int off = 1; off < 1024; off <<= 1) {
        int v   = part[t];
        int add = (t >= off) ? part[t - off] : 0;
        __syncthreads();
        part[t] = v + add;
        __syncthreads();
    }
    int ex = (t == 0) ? 0 : part[t - 1];

    if (t == 0) row_start[0] = 0;
    int run = ex;
    #pragma unroll
    for (int j = 0; j < 32; ++j) {
        cursor[base + j] = run;
        run += local[j];
        row_start[base + j + 1] = run;
    }
}

__global__ void k_scatter(const int* __restrict__ src, const int* __restrict__ dst,
                          const int* __restrict__ et, int* __restrict__ cursor,
                          int* __restrict__ sorted_se)
{
    int e = blockIdx.x * blockDim.x + threadIdx.x;
    if (e < N_EDGES) {
        int p = atomicAdd(&cursor[dst[e]], 1);
        sorted_se[p] = src[e] | (et[e] << 15);
    }
}

// ---------------------------------------------------------------------------
// Gather: a16[n][:] = bf16( sum over incoming edges of bf16 tm[etype][src][:] )
// one 64-lane wave per node; lane owns d=2*lane,2*lane+1; f32 accumulate.
// ---------------------------------------------------------------------------
__global__ __launch_bounds__(256) void k_gather(
    const ushort16* __restrict__ tm, const int* __restrict__ row_start,
    const int* __restrict__ sorted_se, ushort16* __restrict__ a16)
{
    const int node = blockIdx.x * 4 + (threadIdx.x >> 6);
    const int lane = threadIdx.x & 63;
    const int s0 = row_start[node], s1 = row_start[node + 1];

    float ax = 0.f, ay = 0.f;
    int j = s0;
    for (; j + 1 < s1; j += 2) {
        int se0 = sorted_se[j],     se1 = sorted_se[j + 1];
        int sA = se0 & 32767, tA = se0 >> 15;
        int sB = se1 & 32767, tB = se1 >> 15;
        uint32 vA = ((const uint32*)(tm + ((size_t)tA * N_NODES + sA) * D))[lane];
        uint32 vB = ((const uint32*)(tm + ((size_t)tB * N_NODES + sB) * D))[lane];
        ax += bf2f((ushort16)(vA & 0xFFFF)) + bf2f((ushort16)(vB & 0xFFFF));
        ay += bf2f((ushort16)(vA >> 16))    + bf2f((ushort16)(vB >> 16));
    }
    if (j < s1) {
        int se = sorted_se[j];
        int s = se & 32767, t = se >> 15;
        uint32 v = ((const uint32*)(tm + ((size_t)t * N_NODES + s) * D))[lane];
        ax += bf2f((ushort16)(v & 0xFFFF));
        ay += bf2f((ushort16)(v >> 16));
    }
    uint32 packed = ((uint32)f2bf(ay) << 16) | (uint32)f2bf(ax);
    ((uint32*)(a16 + (size_t)node * D))[lane] = packed;
}

// ---------------------------------------------------------------------------
// Pack GRU weights into MFMA B-fragment order (once per launch).
// wp[m][C][ks][lane][8] bf16, m: 0=w_ih 1=w_hh, C: col-block 0..23 (384/16),
// ks: K-step 0..3 (128/32). Fragment: lane l holds B[k=ks*32+(l>>4)*8+j][col=C*16+(l&15)]
// where B[k][col] = w[col][k]  (gi = a @ w^T).
// ---------------------------------------------------------------------------
__global__ void k_pack_w(const float* __restrict__ wih, const float* __restrict__ whh,
                         ushort16* __restrict__ wp)
{
    int idx = blockIdx.x * 256 + threadIdx.x;       // 0 .. 12287
    int m  = idx / 6144;
    int r  = idx % 6144;
    int C  = r >> 8;
    int ks = (r >> 6) & 3;
    int l  = r & 63;
    const float* w = m ? whh : wih;
    int col = C * 16 + (l & 15);
    int k0  = ks * 32 + ((l >> 4) << 3);
    ushort16* dstp = wp + (size_t)idx * 8;
    #pragma unroll
    for (int j = 0; j < 8; ++j)
        dstp[j] = f2bf(w[col * 128 + k0 + j]);
}

// cast feat -> h16 (once per launch)
__global__ void k_cast_h(const float* __restrict__ f, ushort16* __restrict__ h16)
{
    int i = blockIdx.x * 256 + threadIdx.x;         // one float4 per thread
    float4 v = ((const float4*)f)[i];
    ushort4 o;
    o.x = f2bf(v.x); o.y = f2bf(v.y); o.z = f2bf(v.z); o.w = f2bf(v.w);
    ((ushort4*)h16)[i] = o;
}

// ---------------------------------------------------------------------------
// MFMA GRU: h = GRU(a, h). 32 nodes/block, 4 waves, no LDS.
// Wave w: m-tile mt=w>>1 (nodes mt*16..+15), d-blocks db0=(w&1)*4 .. +3.
// Per d-block: acc_r (gi_r+gh_r fused), acc_z, acc_ni, acc_nh; K-loop of 4
// mfma_f32_16x16x32_bf16 steps. C/D layout: col=lane&15 (d), row=(lane>>4)*4+reg (node).
// __syncthreads() between K-loop (reads h16) and epilogue (writes h16):
// wave 1 writes nodes0-15 d64-127 which wave 0 reads as fragments.
// ---------------------------------------------------------------------------
__global__ __launch_bounds__(256) void k_gru_mfma(
    const ushort16* __restrict__ a16, ushort16* __restrict__ h16,
    float* __restrict__ h, const ushort16* __restrict__ wp,
    const float* __restrict__ bih, const float* __restrict__ bhh)
{
    const int tid  = threadIdx.x;
    const int wave = tid >> 6, lane = tid & 63;
    const int mt   = wave >> 1;
    const int db0  = (wave & 1) * 4;
    const int n0   = blockIdx.x * 32;
    const int row  = lane & 15;        // d within 16-block
    const int kgrp = lane >> 4;        // 0..3

    const int nodeA = n0 + mt * 16 + row;   // A-fragment row (node)

    f32x4 accr[4], accz[4], accni[4], accnh[4];
    #pragma unroll
    for (int c = 0; c < 4; ++c) {
        const int d = (db0 + c) * 16 + row;
        float br = bih[d]       + bhh[d];
        float bz = bih[128 + d] + bhh[128 + d];
        float bi = bih[256 + d];
        float bh = bhh[256 + d];
        accr[c]  = (f32x4){br, br, br, br};
        accz[c]  = (f32x4){bz, bz, bz, bz};
        accni[c] = (f32x4){bi, bi, bi, bi};
        accnh[c] = (f32x4){bh, bh, bh, bh};
    }

    const ushort16* abase = a16 + (size_t)nodeA * D + kgrp * 8;
    const ushort16* hbase = h16 + (size_t)nodeA * D + kgrp * 8;

    #pragma unroll
    for (int ks = 0; ks < 4; ++ks) {
        bf16x8 af = *(const bf16x8*)(abase + ks * 32);
        bf16x8 hf = *(const bf16x8*)(hbase + ks * 32);
        #pragma unroll
        for (int c = 0; c < 4; ++c) {
            const int Cr = db0 + c, Cz = 8 + db0 + c, Cn = 16 + db0 + c;
            // slot(m,C,ks,lane) = (((m*24+C)*4+ks)*64+lane)*8 ushorts
            const size_t base0 = (((size_t)(0 * 24 + Cr) * 4 + ks) * 64 + lane) * 8;
            bf16x8 w1r = *(const bf16x8*)(wp + base0);
            bf16x8 w2r = *(const bf16x8*)(wp + base0 + (size_t)24 * 4 * 64 * 8);
            const size_t basez = (((size_t)(0 * 24 + Cz) * 4 + ks) * 64 + lane) * 8;
            bf16x8 w1z = *(const bf16x8*)(wp + basez);
            bf16x8 w2z = *(const bf16x8*)(wp + basez + (size_t)24 * 4 * 64 * 8);
            const size_t basen = (((size_t)(0 * 24 + Cn) * 4 + ks) * 64 + lane) * 8;
            bf16x8 w1n = *(const bf16x8*)(wp + basen);
            bf16x8 w2n = *(const bf16x8*)(wp + basen + (size_t)24 * 4 * 64 * 8);

            accr[c]  = __builtin_amdgcn_mfma_f32_16x16x32_bf16(af, w1r, accr[c], 0, 0, 0);
            accr[c]  = __builtin_amdgcn_mfma_f32_16x16x32_bf16(hf, w2r, accr[c], 0, 0, 0);
            accz[c]  = __builtin_amdgcn_mfma_f32_16x16x32_bf16(af, w1z, accz[c], 0, 0, 0);
            accz[c]  = __builtin_amdgcn_mfma_f32_16x16x32_bf16(hf, w2z, accz[c], 0, 0, 0);
            accni[c] = __builtin_amdgcn_mfma_f32_16x16x32_bf16(af, w1n, accni[c], 0, 0, 0);
            accnh[c] = __builtin_amdgcn_mfma_f32_16x16x32_bf16(hf, w2n, accnh[c], 0, 0, 0);
        }
    }

    __syncthreads();   // all h16/a16 fragment reads done before any h16 writes

    #pragma unroll
    for (int c = 0; c < 4; ++c) {
        const int d = (db0 + c) * 16 + row;
        #pragma unroll
        for (int j = 0; j < 4; ++j) {
            const int node = n0 + mt * 16 + kgrp * 4 + j;
            float r  = 1.f / (1.f + __expf(-accr[c][j]));
            float z  = 1.f / (1.f + __expf(-accz[c][j]));
            float nx = accni[c][j] + r * accnh[c][j];
            float nn = 2.f / (1.f + __expf(-2.f * nx)) - 1.f;   // tanh
            float ho = h[(size_t)node * D + d];
            float hnew = (1.f - z) * nn + z * ho;
            h[(size_t)node * D + d]   = hnew;
            h16[(size_t)node * D + d] = f2bf(hnew);
        }
    }
}

// ---------------------------------------------------------------------------
// Readout: out[g] = sigmoid( sum_nodes(h) . w_cls + b_cls )
// ---------------------------------------------------------------------------
__global__ __launch_bounds__(256) void k_readout(
    const float* __restrict__ h, const float* __restrict__ w_cls,
    const float* __restrict__ b_cls, float* __restrict__ out)
{
    __shared__ float sbuf[256];
    const int g = blockIdx.x;
    const int tid = threadIdx.x;
    const int k = tid & 127, half = tid >> 7;

    float s = 0.f;
    for (int r = half; r < NPG; r += 2)
        s += h[((size_t)g * NPG + r) * D + k];
    sbuf[tid] = s;
    __syncthreads();

    if (tid < 64) {
        int l = tid;
        float v = (sbuf[l]      + sbuf[l + 128]) * w_cls[l]
                + (sbuf[l + 64] + sbuf[l + 192]) * w_cls[l + 64];
        #pragma unroll
        for (int off = 32; off > 0; off >>= 1) v += __shfl_down(v, off);
        if (l == 0) out[g] = 1.f / (1.f + __expf(-(v + b_cls[0])));
    }
}

// ---------------------------------------------------------------------------
extern "C" void kernel_launch(void* const* d_in, const int* in_sizes, int n_in,
                              void* d_out, int out_size, void* d_ws, size_t ws_size,
                              hipStream_t stream)
{
    const float* feat   = (const float*)d_in[0];
    const float* W_edge = (const float*)d_in[1];
    const float* b_edge = (const float*)d_in[2];
    const float* w_ih   = (const float*)d_in[3];
    const float* w_hh   = (const float*)d_in[4];
    const float* b_ih   = (const float*)d_in[5];
    const float* b_hh   = (const float*)d_in[6];
    const float* w_cls  = (const float*)d_in[7];
    const float* b_cls  = (const float*)d_in[8];
    const int*   src    = (const int*)d_in[9];
    const int*   dst    = (const int*)d_in[10];
    const int*   et     = (const int*)d_in[11];
    float* out = (float*)d_out;

    char* ws = (char*)d_ws;
    size_t off = 0;
    auto alloc = [&](size_t bytes) -> void* {
        void* p = ws + off;
        off += (bytes + 255) & ~(size_t)255;
        return p;
    };

    float*    h         = (float*)alloc((size_t)N_NODES * D * 4);
    ushort16* h16       = (ushort16*)alloc((size_t)N_NODES * D * 2);
    ushort16* a16       = (ushort16*)alloc((size_t)N_NODES * D * 2);
    ushort16* tm        = (ushort16*)alloc((size_t)N_ETYPES * N_NODES * D * 2);
    ushort16* wp        = (ushort16*)alloc((size_t)2 * 24 * 4 * 64 * 8 * 2);
    int*      cnt       = (int*)alloc((size_t)N_NODES * 4);
    int*      cursor    = (int*)alloc((size_t)N_NODES * 4);
    int*      row_start = (int*)alloc((size_t)(N_NODES + 1) * 4);
    int*      sorted_se = (int*)alloc((size_t)N_EDGES * 4);

    hipMemcpyAsync(h, feat, (size_t)N_NODES * D * 4, hipMemcpyDeviceToDevice, stream);

    hipMemsetAsync(cnt, 0, (size_t)N_NODES * 4, stream);
    k_hist<<<N_EDGES / 256, 256, 0, stream>>>(dst, cnt);
    k_scan<<<1, 1024, 0, stream>>>(cnt, row_start, cursor);
    k_scatter<<<N_EDGES / 256, 256, 0, stream>>>(src, dst, et, cursor, sorted_se);
    k_pack_w<<<48, 256, 0, stream>>>(w_ih, w_hh, wp);
    k_cast_h<<<(N_NODES * D / 4) / 256, 256, 0, stream>>>(feat, h16);

    for (int step = 0; step < N_STEPS; ++step) {
        k_edge_transform<<<dim3(N_NODES / 64, N_ETYPES), 256, 0, stream>>>(h, W_edge, b_edge, tm);
        k_gather<<<N_NODES / 4, 256, 0, stream>>>(tm, row_start, sorted_se, a16);
        k_gru_mfma<<<N_NODES / 32, 256, 0, stream>>>(a16, h16, h, wp, b_ih, b_hh);
    }

    k_readout<<<N_GRAPHS, 256, 0, stream>>>(h, w_cls, b_cls, out);
}